// Round 1
// 63.730 us; speedup vs baseline: 1.0853x; 1.0853x over previous
//
#include <hip/hip_runtime.h>

// AdderNet forward: out[n,h,w,f] = sum_{dh,dw,c} |Xpad[n,h+dh,w+dw,c] - F[f,dh,dw,c]|
// N=8, H=W=32, C=32, c_out=64, k=3, pad=1. fp32.
//
// R3: filter operand moved to per-lane VGPRs (zero in-loop filter memory ops).
// Lane = (f:8 filters, c8:8 c-chunks of 4 floats). Each lane holds its filter
// slice (9 taps x float4 = 36 VGPRs) for the whole wave lifetime. X is staged
// in LDS and read with uniform-per-f-group addresses (broadcast, banks 4*c8+k
// -> conflict-free). Partial L1-sums over the 8 c-chunks are combined with a
// 3-stage shfl_xor butterfly. Grid 1024 x 256thr -> 4 waves/SIMD.
//
// Block b: n = b>>7, h = (b>>2)&31, w-half = (b>>1)&1 (16 pixels),
// filter-half = b&1 (32 filters; wave supplies 8).
// Per wave: 4 pixel-groups x [18 ds_read_b128 + 288 VALU + 24 shfl/add].

#define BLOCK 256

__global__ __launch_bounds__(256, 4) void adder_fwd(const float* __restrict__ X,
                                                    const float* __restrict__ Fg,
                                                    float* __restrict__ out) {
    __shared__ float Xs[3 * 18 * 32];   // [row 0..2][col 0..17][c 0..31]

    const int b  = blockIdx.x;
    const int fh = b & 1;            // filter half (32 filters)
    const int wh = (b >> 1) & 1;     // w half (16 pixels)
    const int h  = (b >> 2) & 31;
    const int n  = b >> 7;
    const int w0 = wh * 16;
    const int tid = threadIdx.x;

    const int lane = tid & 63;
    const int c8   = lane & 7;       // c-chunk: floats c8*4 .. c8*4+3
    const int f    = lane >> 3;      // 0..7 within the wave's filter group
    const int wave = __builtin_amdgcn_readfirstlane(tid >> 6);
    const int f0   = fh * 32 + wave * 8;
    const int fid  = f0 + f;

    // ---- filter slice -> registers (before the barrier, overlaps staging).
    // 9 taps x 4 floats; lanes c8=0..7 cover the 32 channels contiguously.
    float4 fr[9];
    {
        const float* fp = Fg + (size_t)fid * 288 + c8 * 4;
        #pragma unroll
        for (int t = 0; t < 9; ++t)
            fr[t] = *(const float4*)(fp + t * 32);
    }

    // ---- stage X rows h-1..h+1, cols w0-1..w0+16 (zero padded): 432 float4
    #pragma unroll
    for (int it = 0; it < 2; ++it) {
        int idx = tid + BLOCK * it;
        if (idx < 432) {
            int c4  = idx & 7;
            int t   = idx >> 3;          // 0..53 = row*18 + col
            int col = t % 18;
            int row = t / 18;
            int hr  = h + row - 1;
            int gw  = w0 + col - 1;
            float4 v = make_float4(0.f, 0.f, 0.f, 0.f);
            if ((unsigned)hr < 32u && (unsigned)gw < 32u)
                v = ((const float4*)(X + (((size_t)n * 32 + hr) * 32 + gw) * 32))[c4];
            ((float4*)(Xs + (row * 18 + col) * 32))[c4] = v;
        }
    }
    __syncthreads();

    const float* xb = Xs + c8 * 4;
    const size_t obase = (((size_t)n * 32 + h) * 32 + w0) * 64 + fid;

    #pragma unroll 1
    for (int pg = 0; pg < 4; ++pg) {
        float4 acc[4];
        #pragma unroll
        for (int pp = 0; pp < 4; ++pp)
            acc[pp] = make_float4(0.f, 0.f, 0.f, 0.f);

        #pragma unroll
        for (int dh = 0; dh < 3; ++dh) {
            // 6 columns cover the 4 pixels' 3-wide windows at this row.
            float4 x[6];
            #pragma unroll
            for (int j = 0; j < 6; ++j)
                x[j] = *(const float4*)(xb + (dh * 18 + pg * 4 + j) * 32);

            #pragma unroll
            for (int dw = 0; dw < 3; ++dw) {
                const float4 fv = fr[dh * 3 + dw];
                #pragma unroll
                for (int pp = 0; pp < 4; ++pp) {
                    const float4 xv = x[pp + dw];
                    acc[pp].x += fabsf(xv.x - fv.x);
                    acc[pp].y += fabsf(xv.y - fv.y);
                    acc[pp].z += fabsf(xv.z - fv.z);
                    acc[pp].w += fabsf(xv.w - fv.w);
                }
            }
        }

        // horizontal sum per pixel, then reduce over the 8 c-chunks (lane bits 0..2)
        float s0 = (acc[0].x + acc[0].y) + (acc[0].z + acc[0].w);
        float s1 = (acc[1].x + acc[1].y) + (acc[1].z + acc[1].w);
        float s2 = (acc[2].x + acc[2].y) + (acc[2].z + acc[2].w);
        float s3 = (acc[3].x + acc[3].y) + (acc[3].z + acc[3].w);

        s0 += __shfl_xor(s0, 1, 64);  s1 += __shfl_xor(s1, 1, 64);
        s2 += __shfl_xor(s2, 1, 64);  s3 += __shfl_xor(s3, 1, 64);
        s0 += __shfl_xor(s0, 2, 64);  s1 += __shfl_xor(s1, 2, 64);
        s2 += __shfl_xor(s2, 2, 64);  s3 += __shfl_xor(s3, 2, 64);
        s0 += __shfl_xor(s0, 4, 64);  s1 += __shfl_xor(s1, 4, 64);
        s2 += __shfl_xor(s2, 4, 64);  s3 += __shfl_xor(s3, 4, 64);

        // lanes c8=0..3 each store one pixel (all lanes hold all 4 sums)
        if (c8 < 4) {
            float v = s0;
            if (c8 == 1) v = s1;
            else if (c8 == 2) v = s2;
            else if (c8 == 3) v = s3;
            out[obase + (size_t)(pg * 4 + c8) * 64] = v;
        }
    }
}

extern "C" void kernel_launch(void* const* d_in, const int* in_sizes, int n_in,
                              void* d_out, int out_size, void* d_ws, size_t ws_size,
                              hipStream_t stream) {
    const float* X = (const float*)d_in[0];
    const float* F = (const float*)d_in[1];
    float* out = (float*)d_out;
    adder_fwd<<<dim3(1024), dim3(256), 0, stream>>>(X, F, out);
}

// Round 2
// 62.757 us; speedup vs baseline: 1.1022x; 1.0155x over previous
//
#include <hip/hip_runtime.h>

// AdderNet forward: out[n,h,w,f] = sum_{dh,dw,c} |Xpad[n,h+dh,w+dw,c] - F[f,dh,dw,c]|
// N=8, H=W=32, C=32, c_out=64, k=3, pad=1. fp32.
//
// R4: kill exposed latency.
//  (1) Cross-lane c-reduction via DPP (VALU latency ~5cyc/stage) instead of
//      __shfl_xor -> ds_bpermute (~120cyc/stage, 3 dependent stages).
//      xor1 = quad_perm(1,0,3,2)=0xB1, xor2 = quad_perm(2,3,0,1)=0x4E,
//      then row_half_mirror(0x141) == xor4 once value is quad-uniform.
//  (2) Software-pipelined LDS reads: ping-pong xA/xB register buffers, the
//      batch for step k+1 issues before the compute of step k, pg loop fully
//      unrolled so loads flow across pixel-group boundaries.
// Lane = (f:8, c8:8 chunks of 4 channels); filters register-resident (fr[9]).
// Grid 1024 x 256thr -> 4 waves/SIMD.

#define BLOCK 256

template <int CTRL>
__device__ __forceinline__ float dpp_add(float s) {
    int t = __builtin_amdgcn_update_dpp(0, __float_as_int(s), CTRL, 0xf, 0xf, true);
    return s + __int_as_float(t);
}

__global__ __launch_bounds__(256, 4) void adder_fwd(const float* __restrict__ X,
                                                    const float* __restrict__ Fg,
                                                    float* __restrict__ out) {
    __shared__ float Xs[3 * 18 * 32];   // [row 0..2][col 0..17][c 0..31]

    const int b  = blockIdx.x;
    const int fh = b & 1;            // filter half (32 filters)
    const int wh = (b >> 1) & 1;     // w half (16 pixels)
    const int h  = (b >> 2) & 31;
    const int n  = b >> 7;
    const int w0 = wh * 16;
    const int tid = threadIdx.x;

    const int lane = tid & 63;
    const int c8   = lane & 7;       // c-chunk: floats c8*4 .. c8*4+3
    const int f    = lane >> 3;      // 0..7 within the wave's filter group
    const int wave = __builtin_amdgcn_readfirstlane(tid >> 6);
    const int fid  = fh * 32 + wave * 8 + f;

    // ---- filter slice -> registers (9 taps x float4 = 36 VGPRs)
    float4 fr[9];
    {
        const float* fp = Fg + (size_t)fid * 288 + c8 * 4;
        #pragma unroll
        for (int t = 0; t < 9; ++t)
            fr[t] = *(const float4*)(fp + t * 32);
    }

    // ---- stage X rows h-1..h+1, cols w0-1..w0+16 (zero padded): 432 float4
    #pragma unroll
    for (int it = 0; it < 2; ++it) {
        int idx = tid + BLOCK * it;
        if (idx < 432) {
            int c4  = idx & 7;
            int t   = idx >> 3;          // 0..53 = row*18 + col
            int col = t % 18;
            int row = t / 18;
            int hr  = h + row - 1;
            int gw  = w0 + col - 1;
            float4 v = make_float4(0.f, 0.f, 0.f, 0.f);
            if ((unsigned)hr < 32u && (unsigned)gw < 32u)
                v = ((const float4*)(X + (((size_t)n * 32 + hr) * 32 + gw) * 32))[c4];
            ((float4*)(Xs + (row * 18 + col) * 32))[c4] = v;
        }
    }
    __syncthreads();

    const float* xb = Xs + c8 * 4;
    const size_t obase = (((size_t)n * 32 + h) * 32 + w0) * 64 + fid;

    // 6-column batch load (one dh row of one pixel-group's windows)
    auto LD = [&](float4* dst, int dh, int col0) {
        #pragma unroll
        for (int j = 0; j < 6; ++j)
            dst[j] = *(const float4*)(xb + (dh * 18 + col0 + j) * 32);
    };
    // 3 taps x 4 pixels of |x-f| accumulation from a 6-column batch
    auto COMP = [&](const float4* xx, int t0, float4* acc) {
        #pragma unroll
        for (int dw = 0; dw < 3; ++dw) {
            const float4 fv = fr[t0 + dw];
            #pragma unroll
            for (int pp = 0; pp < 4; ++pp) {
                const float4 xv = xx[pp + dw];
                acc[pp].x += fabsf(xv.x - fv.x);
                acc[pp].y += fabsf(xv.y - fv.y);
                acc[pp].z += fabsf(xv.z - fv.z);
                acc[pp].w += fabsf(xv.w - fv.w);
            }
        }
    };

    float4 xA[6], xB[6];
    LD(xA, 0, 0);                       // preload pg=0, dh=0

    #pragma unroll
    for (int pg = 0; pg < 4; ++pg) {
        float4 acc[4];
        #pragma unroll
        for (int pp = 0; pp < 4; ++pp)
            acc[pp] = make_float4(0.f, 0.f, 0.f, 0.f);

        // ping-pong parity is compile-time (pg fully unrolled)
        float4* b0 = ((pg & 1) == 0) ? xA : xB;   // holds current dh=0 data
        float4* b1 = ((pg & 1) == 0) ? xB : xA;

        LD(b1, 1, pg * 4);              // fetch dh=1
        COMP(b0, 0, acc);               // compute dh=0
        LD(b0, 2, pg * 4);              // fetch dh=2
        COMP(b1, 3, acc);               // compute dh=1
        if (pg < 3) LD(b1, 0, (pg + 1) * 4);   // fetch next pg's dh=0
        COMP(b0, 6, acc);               // compute dh=2

        // horizontal sum per pixel
        float s0 = (acc[0].x + acc[0].y) + (acc[0].z + acc[0].w);
        float s1 = (acc[1].x + acc[1].y) + (acc[1].z + acc[1].w);
        float s2 = (acc[2].x + acc[2].y) + (acc[2].z + acc[2].w);
        float s3 = (acc[3].x + acc[3].y) + (acc[3].z + acc[3].w);

        // reduce over the 8 c-chunks (lane bits 0..2) entirely on the VALU
        s0 = dpp_add<0xB1>(s0);  s1 = dpp_add<0xB1>(s1);
        s2 = dpp_add<0xB1>(s2);  s3 = dpp_add<0xB1>(s3);
        s0 = dpp_add<0x4E>(s0);  s1 = dpp_add<0x4E>(s1);
        s2 = dpp_add<0x4E>(s2);  s3 = dpp_add<0x4E>(s3);
        s0 = dpp_add<0x141>(s0); s1 = dpp_add<0x141>(s1);
        s2 = dpp_add<0x141>(s2); s3 = dpp_add<0x141>(s3);

        // lanes c8=0..3 each store one pixel (all lanes hold all 4 sums)
        if (c8 < 4) {
            float v = s0;
            if (c8 == 1) v = s1;
            else if (c8 == 2) v = s2;
            else if (c8 == 3) v = s3;
            out[obase + (size_t)(pg * 4 + c8) * 64] = v;
        }
    }
}

extern "C" void kernel_launch(void* const* d_in, const int* in_sizes, int n_in,
                              void* d_out, int out_size, void* d_ws, size_t ws_size,
                              hipStream_t stream) {
    const float* X = (const float*)d_in[0];
    const float* F = (const float*)d_in[1];
    float* out = (float*)d_out;
    adder_fwd<<<dim3(1024), dim3(256), 0, stream>>>(X, F, out);
}

// Round 3
// 62.689 us; speedup vs baseline: 1.1034x; 1.0011x over previous
//
#include <hip/hip_runtime.h>

// AdderNet forward: out[n,h,w,f] = sum_{dh,dw,c} |Xpad[n,h+dh,w+dw,c] - F[f,dh,dw,c]|
// N=8, H=W=32, C=32, c_out=64, k=3, pad=1. fp32.
//
// R5: 512-thread blocks — one block covers (n, h, w-half) x ALL 64 filters.
// 8 waves/block, wave = filter-octet. Grid 512 -> 2 blocks/CU -> 4 waves/SIMD
// (same TLP as R4) but X-tile staging + prologue work is paid HALF as often,
// and staging is a single non-looped pass (432 float4 < 512 threads).
// Lane = (f:8, c8:8 chunks of 4 channels); filters register-resident fr[9].
// Inner loop: per pixel-group ping-pong LDS batches (hand-unrolled, named
// buffers), DPP c-reduction (quad_perm 0xB1 / 0x4E, row_half_mirror 0x141).

#define BLOCK 512

template <int CTRL>
__device__ __forceinline__ float dpp_add(float s) {
    int t = __builtin_amdgcn_update_dpp(0, __float_as_int(s), CTRL, 0xf, 0xf, true);
    return s + __int_as_float(t);
}

__global__ __launch_bounds__(512, 4) void adder_fwd(const float* __restrict__ X,
                                                    const float* __restrict__ Fg,
                                                    float* __restrict__ out) {
    __shared__ float Xs[3 * 18 * 32];   // [row 0..2][col 0..17][c 0..31]

    const int b  = blockIdx.x;          // 512 = n(8) x h(32) x wh(2)
    const int wh = b & 1;
    const int h  = (b >> 1) & 31;
    const int n  = b >> 6;
    const int w0 = wh * 16;
    const int tid = threadIdx.x;

    const int lane = tid & 63;
    const int c8   = lane & 7;          // c-chunk: floats c8*4 .. c8*4+3
    const int f    = lane >> 3;         // 0..7 within the wave's filter octet
    const int wave = __builtin_amdgcn_readfirstlane(tid >> 6);
    const int fid  = wave * 8 + f;      // 0..63

    // ---- filter slice -> registers (9 taps x float4 = 36 VGPRs)
    float4 fr[9];
    {
        const float* fp = Fg + (size_t)fid * 288 + c8 * 4;
        #pragma unroll
        for (int t = 0; t < 9; ++t)
            fr[t] = *(const float4*)(fp + t * 32);
    }

    // ---- stage X rows h-1..h+1, cols w0-1..w0+16 (zero padded): 432 float4,
    // single pass over 512 threads.
    if (tid < 432) {
        int c4  = tid & 7;
        int t   = tid >> 3;             // 0..53 = row*18 + col
        int col = t % 18;
        int row = t / 18;
        int hr  = h + row - 1;
        int gw  = w0 + col - 1;
        float4 v = make_float4(0.f, 0.f, 0.f, 0.f);
        if ((unsigned)hr < 32u && (unsigned)gw < 32u)
            v = ((const float4*)(X + (((size_t)n * 32 + hr) * 32 + gw) * 32))[c4];
        ((float4*)(Xs + (row * 18 + col) * 32))[c4] = v;
    }
    __syncthreads();

    const float* xb = Xs + c8 * 4;
    const size_t obase = (((size_t)n * 32 + h) * 32 + w0) * 64 + fid;

    float4 xA[6], xB[6], acc[4];

#define LD(dst, dh, col0)                                                   \
    {                                                                       \
        _Pragma("unroll")                                                   \
        for (int j = 0; j < 6; ++j)                                         \
            dst[j] = *(const float4*)(xb + ((dh) * 18 + (col0) + j) * 32);  \
    }

#define COMP(xx, t0)                                                        \
    {                                                                       \
        _Pragma("unroll")                                                   \
        for (int dw = 0; dw < 3; ++dw) {                                    \
            const float4 fv = fr[(t0) + dw];                                \
            _Pragma("unroll")                                               \
            for (int pp = 0; pp < 4; ++pp) {                                \
                const float4 xv = xx[pp + dw];                              \
                acc[pp].x += fabsf(xv.x - fv.x);                            \
                acc[pp].y += fabsf(xv.y - fv.y);                            \
                acc[pp].z += fabsf(xv.z - fv.z);                            \
                acc[pp].w += fabsf(xv.w - fv.w);                            \
            }                                                               \
        }                                                                   \
    }

#define PG(pg, B0, B1, LAST)                                                \
    {                                                                       \
        _Pragma("unroll")                                                   \
        for (int pp = 0; pp < 4; ++pp)                                      \
            acc[pp] = make_float4(0.f, 0.f, 0.f, 0.f);                      \
        LD(B1, 1, (pg) * 4);            /* fetch dh=1 */                    \
        COMP(B0, 0);                    /* compute dh=0 */                  \
        LD(B0, 2, (pg) * 4);            /* fetch dh=2 */                    \
        COMP(B1, 3);                    /* compute dh=1 */                  \
        if (!(LAST)) LD(B1, 0, ((pg) + 1) * 4);  /* next pg's dh=0 */       \
        COMP(B0, 6);                    /* compute dh=2 */                  \
        float s0 = (acc[0].x + acc[0].y) + (acc[0].z + acc[0].w);           \
        float s1 = (acc[1].x + acc[1].y) + (acc[1].z + acc[1].w);           \
        float s2 = (acc[2].x + acc[2].y) + (acc[2].z + acc[2].w);           \
        float s3 = (acc[3].x + acc[3].y) + (acc[3].z + acc[3].w);           \
        s0 = dpp_add<0xB1>(s0);  s1 = dpp_add<0xB1>(s1);                    \
        s2 = dpp_add<0xB1>(s2);  s3 = dpp_add<0xB1>(s3);                    \
        s0 = dpp_add<0x4E>(s0);  s1 = dpp_add<0x4E>(s1);                    \
        s2 = dpp_add<0x4E>(s2);  s3 = dpp_add<0x4E>(s3);                    \
        s0 = dpp_add<0x141>(s0); s1 = dpp_add<0x141>(s1);                   \
        s2 = dpp_add<0x141>(s2); s3 = dpp_add<0x141>(s3);                   \
        if (c8 < 4) {                                                       \
            float v = s0;                                                   \
            if (c8 == 1) v = s1;                                            \
            else if (c8 == 2) v = s2;                                       \
            else if (c8 == 3) v = s3;                                       \
            out[obase + (size_t)((pg) * 4 + c8) * 64] = v;                  \
        }                                                                   \
    }

    LD(xA, 0, 0);                       // preload pg=0, dh=0
    PG(0, xA, xB, 0)
    PG(1, xB, xA, 0)
    PG(2, xA, xB, 0)
    PG(3, xB, xA, 1)

#undef PG
#undef COMP
#undef LD
}

extern "C" void kernel_launch(void* const* d_in, const int* in_sizes, int n_in,
                              void* d_out, int out_size, void* d_ws, size_t ws_size,
                              hipStream_t stream) {
    const float* X = (const float*)d_in[0];
    const float* F = (const float*)d_in[1];
    float* out = (float*)d_out;
    adder_fwd<<<dim3(512), dim3(512), 0, stream>>>(X, F, out);
}